// Round 11
// baseline (155.517 us; speedup 1.0000x reference)
//
#include <hip/hip_runtime.h>
#include <hip/hip_bf16.h>

#define BB 4
#define CC 128
#define TWOC 256
#define NN 4096
#define KK 16
#define COUT 256
#define BNK (BB*NN*KK)      // 262144
#define NODES (BB*NN)       // 16384

typedef __attribute__((ext_vector_type(8))) short short8;
typedef __attribute__((ext_vector_type(4))) float f32x4;

static __device__ __forceinline__ unsigned short f2bs(float f) {
  union { __hip_bfloat16 h; unsigned short s; } u;
  u.h = __float2bfloat16(f);
  return u.s;
}
static __device__ __forceinline__ float bs2f(unsigned short s) {
  union { unsigned int u; float f; } v;
  v.u = ((unsigned int)s) << 16;
  return v.f;
}

// K0: transpose x [B][C][N] f32 -> featbf [B*N][128] bf16;
//     pack W12 [512 col][128 k] bf16: col<256 -> W_L - W_R, col>=256 -> W_R; zero stats.
__global__ void __launch_bounds__(256) k0_prep(const float* __restrict__ x,
                                               unsigned short* __restrict__ featbf,
                                               const float* __restrict__ w,
                                               unsigned short* __restrict__ w12,
                                               float* __restrict__ gsum,
                                               float* __restrict__ gsq) {
  __shared__ float tile[64][129];
  int b = blockIdx.x >> 6;
  int n0 = (blockIdx.x & 63) << 6;
  int t = threadIdx.x;
  if (blockIdx.x == 0) { gsum[t] = 0.f; gsq[t] = 0.f; }
  {
    int flat = blockIdx.x * 256 + t;      // 0..65535 over [512][128]
    int col = flat >> 7, k = flat & 127;
    float v = (col < COUT) ? (w[col * TWOC + k] - w[col * TWOC + CC + k])
                           : w[(col - COUT) * TWOC + CC + k];
    w12[flat] = f2bs(v);
  }
#pragma unroll
  for (int i = 0; i < 32; ++i) {
    int flat = t + i * 256;
    int c = flat >> 6;
    int nl = flat & 63;
    tile[nl][c] = x[((size_t)(b * CC + c) * NN) + n0 + nl];
  }
  __syncthreads();
#pragma unroll
  for (int i = 0; i < 8; ++i) {
    int e = t + i * 256;
    int c4 = (e & 31) << 2;
    int nl = e >> 5;
    ushort4 u;
    u.x = f2bs(tile[nl][c4 + 0]);
    u.y = f2bs(tile[nl][c4 + 1]);
    u.z = f2bs(tile[nl][c4 + 2]);
    u.w = f2bs(tile[nl][c4 + 3]);
    *(ushort4*)(featbf + ((size_t)(b * NN + n0 + nl) * CC + c4)) = u;
  }
}

// K1: dense streaming GEMM Y[16384][512] = feat[16384][128] @ W12^T. No LDS, no
// gathers. 4 waves/block, each wave 32 cols x 64 rows (4 iters of 16 rows),
// W-frags register-resident (32 VGPR), A double-buffered. Batch->XCD pinned.
__global__ void __launch_bounds__(256, 4) k1_gemm(
    const unsigned short* __restrict__ featbf,
    const unsigned short* __restrict__ w12,
    unsigned short* __restrict__ Y)
{
  const int tid = threadIdx.x;
  const int wv   = tid >> 6;
  const int lane = tid & 63;
  const int l15  = lane & 15;
  const int lhi  = lane >> 4;
  const int bid  = blockIdx.x;
  // batch pinned to XCD pair: xcd = bid&7 -> b = xcd>>1
  const int b = (bid & 7) >> 1;
  const int inner = ((bid >> 3) << 1) | (bid & 1);   // 0..255 within batch
  const int rb = inner >> 2;                          // 0..63 rowblock (64 rows)
  const int cg = (inner & 3) * 4 + wv;                // 0..15 colgroup
  const int colbase = cg * 32;
  const int row0 = b * NN + rb * 64;

  short8 wf[4][2];
#pragma unroll
  for (int t = 0; t < 4; ++t)
#pragma unroll
    for (int ct = 0; ct < 2; ++ct)
      wf[t][ct] = *(const short8*)(w12 + (size_t)(colbase + ct * 16 + l15) * CC + t * 32 + lhi * 8);

  short8 aA[4], aB[4];
#pragma unroll
  for (int t = 0; t < 4; ++t)
    aA[t] = *(const short8*)(featbf + (size_t)(row0 + l15) * CC + t * 32 + lhi * 8);

#pragma unroll
  for (int it = 0; it < 4; ++it) {
    short8* cur = (it & 1) ? aB : aA;
    short8* nxt = (it & 1) ? aA : aB;
    if (it < 3) {
      int r = row0 + (it + 1) * 16 + l15;
#pragma unroll
      for (int t = 0; t < 4; ++t)
        nxt[t] = *(const short8*)(featbf + (size_t)r * CC + t * 32 + lhi * 8);
    }
    f32x4 acc0 = {}, acc1 = {};
#pragma unroll
    for (int t = 0; t < 4; ++t) {
      acc0 = __builtin_amdgcn_mfma_f32_16x16x32_bf16(cur[t], wf[t][0], acc0, 0, 0, 0);
      acc1 = __builtin_amdgcn_mfma_f32_16x16x32_bf16(cur[t], wf[t][1], acc1, 0, 0, 0);
    }
    const int orow0 = row0 + it * 16;
#pragma unroll
    for (int i = 0; i < 4; ++i) {
      unsigned short* yr = Y + (size_t)(orow0 + lhi * 4 + i) * 512 + colbase + l15;
      yr[0]  = f2bs(acc0[i]);
      yr[16] = f2bs(acc1[i]);
    }
  }
}

// K2: edge phase, latency-optimized. 2048 blocks, 2 nodes/wave; both nodes'
// index vectors pre-loaded; all 32 Y-row loads of a node issued as one batch
// into registers before compute (deep MLP). Batch->XCD pinned for Y locality.
__global__ void __launch_bounds__(256, 2) k2_edge(
    const unsigned short* __restrict__ Y,
    const float* __restrict__ bias,
    const int* __restrict__ eidx,
    unsigned short* __restrict__ nmaxh, unsigned short* __restrict__ nminh,
    float* __restrict__ gsum, float* __restrict__ gsq)
{
  __shared__ float sred[2][4][256];
  const int tid = threadIdx.x;
  const int wv   = tid >> 6;
  const int lane = tid & 63;
  const int bid  = blockIdx.x;                        // 0..2047
  const int b = (bid & 7) >> 1;
  const int inner = ((bid >> 3) << 1) | (bid & 1);    // 0..511
  const int nbase = b * NN + inner * 8 + wv * 2;      // 2 nodes per wave
  const int c0 = lane * 4;

  const float4 bv = *(const float4*)(bias + c0);
  const unsigned short* Yb = Y + (size_t)b * NN * 512;

  float ssum[4] = {0.f, 0.f, 0.f, 0.f};
  float ssq[4]  = {0.f, 0.f, 0.f, 0.f};

  // pre-load BOTH nodes' edge indices up front (hides idx latency under node0)
  const int* e0 = eidx + (size_t)nbase * KK;   // node0 x_j
  const int* e1 = e0 + BNK;                    // node0 x_i
  int4 ejA[4], eiA[4], ejB[4], eiB[4];
#pragma unroll
  for (int u = 0; u < 4; ++u) {
    ejA[u] = *(const int4*)(e0 + u * 4);
    eiA[u] = *(const int4*)(e1 + u * 4);
  }
#pragma unroll
  for (int u = 0; u < 4; ++u) {
    ejB[u] = *(const int4*)(e0 + KK + u * 4);
    eiB[u] = *(const int4*)(e1 + KK + u * 4);
  }

  auto donode = [&](int node, const int4 (&ej4)[4], const int4 (&ei4)[4]) {
    const int* ejp = (const int*)ej4;
    const int* eip = (const int*)ei4;
    // batch-issue all 32 row loads (independent -> deep MLP)
    ushort4 uu[16], vv[16];
#pragma unroll
    for (int e = 0; e < 16; ++e) {
      uu[e] = *(const ushort4*)(Yb + (size_t)eip[e] * 512 + c0);
      vv[e] = *(const ushort4*)(Yb + (size_t)ejp[e] * 512 + 256 + c0);
    }
    float mx[4] = {0.f, 0.f, 0.f, 0.f};
    float mn[4] = {1e30f, 1e30f, 1e30f, 1e30f};
#pragma unroll
    for (int e = 0; e < 16; ++e) {
      float y0 = fmaxf(bs2f(uu[e].x) + bs2f(vv[e].x) + bv.x, 0.f);
      float y1 = fmaxf(bs2f(uu[e].y) + bs2f(vv[e].y) + bv.y, 0.f);
      float y2 = fmaxf(bs2f(uu[e].z) + bs2f(vv[e].z) + bv.z, 0.f);
      float y3 = fmaxf(bs2f(uu[e].w) + bs2f(vv[e].w) + bv.w, 0.f);
      mx[0] = fmaxf(mx[0], y0); mn[0] = fminf(mn[0], y0); ssum[0] += y0; ssq[0] += y0 * y0;
      mx[1] = fmaxf(mx[1], y1); mn[1] = fminf(mn[1], y1); ssum[1] += y1; ssq[1] += y1 * y1;
      mx[2] = fmaxf(mx[2], y2); mn[2] = fminf(mn[2], y2); ssum[2] += y2; ssq[2] += y2 * y2;
      mx[3] = fmaxf(mx[3], y3); mn[3] = fminf(mn[3], y3); ssum[3] += y3; ssq[3] += y3 * y3;
    }
    ushort4 om, on;
    om.x = f2bs(mx[0]); om.y = f2bs(mx[1]); om.z = f2bs(mx[2]); om.w = f2bs(mx[3]);
    on.x = f2bs(mn[0]); on.y = f2bs(mn[1]); on.z = f2bs(mn[2]); on.w = f2bs(mn[3]);
    *(ushort4*)(nmaxh + (size_t)node * COUT + c0) = om;
    *(ushort4*)(nminh + (size_t)node * COUT + c0) = on;
  };

  donode(nbase,     ejA, eiA);
  donode(nbase + 1, ejB, eiB);

#pragma unroll
  for (int m = 0; m < 4; ++m) {
    sred[0][wv][c0 + m] = ssum[m];
    sred[1][wv][c0 + m] = ssq[m];
  }
  __syncthreads();
  {
    const int c = tid;   // 0..255
    float s = sred[0][0][c] + sred[0][1][c] + sred[0][2][c] + sred[0][3][c];
    float q = sred[1][0][c] + sred[1][1][c] + sred[1][2][c] + sred[1][3][c];
    atomicAdd(&gsum[c], s);
    atomicAdd(&gsq[c], q);
  }
}

// K3: BN-affine finalize + monotone max/min select (bf16 in) + transposed output
__global__ void __launch_bounds__(256) k3_out(const unsigned short* __restrict__ nmaxh,
                                              const unsigned short* __restrict__ nminh,
                                              const float* __restrict__ gsum,
                                              const float* __restrict__ gsq,
                                              const float* __restrict__ gamma,
                                              const float* __restrict__ beta,
                                              float* __restrict__ out) {
  __shared__ float tile[COUT][33];
  int b = blockIdx.x >> 7;
  int n0 = (blockIdx.x & 127) << 5;
  int t = threadIdx.x;
  const float inv = 1.0f / (float)BNK;
  float mean = gsum[t] * inv;
  float var  = gsq[t] * inv - mean * mean;
  float sc = gamma[t] * rsqrtf(var + 1e-5f);
  float sh = beta[t] - mean * sc;
  const unsigned short* src = (sc >= 0.f) ? nmaxh : nminh;
#pragma unroll
  for (int rr = 0; rr < 32; ++rr) {
    size_t g = (size_t)(b * NN + n0 + rr) * COUT + t;
    tile[t][rr] = bs2f(src[g]) * sc + sh;
  }
  __syncthreads();
#pragma unroll
  for (int i = 0; i < 32; ++i) {
    int o = i * 8 + (t >> 5);
    int nl = t & 31;
    out[((size_t)(b * COUT + o) * NN) + n0 + nl] = tile[o][nl];
  }
}

extern "C" void kernel_launch(void* const* d_in, const int* in_sizes, int n_in,
                              void* d_out, int out_size, void* d_ws, size_t ws_size,
                              hipStream_t stream) {
  const float* x     = (const float*)d_in[0];
  const float* w     = (const float*)d_in[1];
  const float* bias  = (const float*)d_in[2];
  const float* gamma = (const float*)d_in[3];
  const float* beta  = (const float*)d_in[4];
  const int*   eidx  = (const int*)d_in[5];

  // ws layout (33.6 MB; featbf/w12 lifetimes end at k1, overlapped by nmaxh):
  char* ws = (char*)d_ws;
  unsigned short* featbf = (unsigned short*)(ws);              // @0        4,194,304 B (dead after k1)
  unsigned short* w12    = (unsigned short*)(ws + 4194304);    // @4194304    131,072 B (dead after k1)
  unsigned short* nmaxh  = (unsigned short*)(ws);              // @0        8,388,608 B (written in k2)
  unsigned short* Ybuf   = (unsigned short*)(ws + 8388608);    // @8388608 16,777,216 B
  unsigned short* nminh  = (unsigned short*)(ws + 25165824);   // @25165824 8,388,608 B
  float* gsum = (float*)(ws + 33554432);                       //     1,024 B
  float* gsq  = (float*)(ws + 33555456);                       //     1,024 B
  float* out = (float*)d_out;

  k0_prep<<<256, 256, 0, stream>>>(x, featbf, w, w12, gsum, gsq);
  k1_gemm<<<1024, 256, 0, stream>>>(featbf, w12, Ybuf);
  k2_edge<<<2048, 256, 0, stream>>>(Ybuf, bias, eidx, nmaxh, nminh, gsum, gsq);
  k3_out<<<512, 256, 0, stream>>>(nmaxh, nminh, gsum, gsq, gamma, beta, out);
}

// Round 12
// 128.084 us; speedup vs baseline: 1.2142x; 1.2142x over previous
//
#include <hip/hip_runtime.h>
#include <hip/hip_bf16.h>

#define BB 4
#define CC 128
#define TWOC 256
#define NN 4096
#define KK 16
#define COUT 256
#define BNK (BB*NN*KK)      // 262144
#define NODES (BB*NN)       // 16384

typedef __attribute__((ext_vector_type(8))) short short8;
typedef __attribute__((ext_vector_type(4))) float f32x4;

static __device__ __forceinline__ unsigned short f2bs(float f) {
  union { __hip_bfloat16 h; unsigned short s; } u;
  u.h = __float2bfloat16(f);
  return u.s;
}
static __device__ __forceinline__ float bs2f(unsigned short s) {
  union { unsigned int u; float f; } v;
  v.u = ((unsigned int)s) << 16;
  return v.f;
}

// K0: transpose x [B][C][N] f32 -> featbf [B*N][128] bf16;
//     pack W12 [512 col][128 k] bf16: col<256 -> W_L - W_R, col>=256 -> W_R;
//     zero the 64-slot stats partial buffers (32768 floats).
__global__ void __launch_bounds__(256) k0_prep(const float* __restrict__ x,
                                               unsigned short* __restrict__ featbf,
                                               const float* __restrict__ w,
                                               unsigned short* __restrict__ w12,
                                               float* __restrict__ gpart) {
  __shared__ float tile[64][129];
  int b = blockIdx.x >> 6;
  int n0 = (blockIdx.x & 63) << 6;
  int t = threadIdx.x;
  if (blockIdx.x < 128) gpart[blockIdx.x * 256 + t] = 0.f;
  {
    int flat = blockIdx.x * 256 + t;      // 0..65535 over [512][128]
    int col = flat >> 7, k = flat & 127;
    float v = (col < COUT) ? (w[col * TWOC + k] - w[col * TWOC + CC + k])
                           : w[(col - COUT) * TWOC + CC + k];
    w12[flat] = f2bs(v);
  }
#pragma unroll
  for (int i = 0; i < 32; ++i) {
    int flat = t + i * 256;
    int c = flat >> 6;
    int nl = flat & 63;
    tile[nl][c] = x[((size_t)(b * CC + c) * NN) + n0 + nl];
  }
  __syncthreads();
#pragma unroll
  for (int i = 0; i < 8; ++i) {
    int e = t + i * 256;
    int c4 = (e & 31) << 2;
    int nl = e >> 5;
    ushort4 u;
    u.x = f2bs(tile[nl][c4 + 0]);
    u.y = f2bs(tile[nl][c4 + 1]);
    u.z = f2bs(tile[nl][c4 + 2]);
    u.w = f2bs(tile[nl][c4 + 3]);
    *(ushort4*)(featbf + ((size_t)(b * NN + n0 + nl) * CC + c4)) = u;
  }
}

// K1: dense streaming GEMM Y[16384][512] = feat @ W12^T; bias folded into the
// U-half (cols<256) before the bf16 round. W-frags register-resident.
__global__ void __launch_bounds__(256, 4) k1_gemm(
    const unsigned short* __restrict__ featbf,
    const unsigned short* __restrict__ w12,
    const float* __restrict__ bias,
    unsigned short* __restrict__ Y)
{
  const int tid = threadIdx.x;
  const int wv   = tid >> 6;
  const int lane = tid & 63;
  const int l15  = lane & 15;
  const int lhi  = lane >> 4;
  const int bid  = blockIdx.x;
  const int b = (bid & 7) >> 1;
  const int inner = ((bid >> 3) << 1) | (bid & 1);   // 0..255 within batch
  const int rb = inner >> 2;                          // 0..63 rowblock (64 rows)
  const int cg = (inner & 3) * 4 + wv;                // 0..15 colgroup
  const int colbase = cg * 32;
  const int row0 = b * NN + rb * 64;

  short8 wf[4][2];
#pragma unroll
  for (int t = 0; t < 4; ++t)
#pragma unroll
    for (int ct = 0; ct < 2; ++ct)
      wf[t][ct] = *(const short8*)(w12 + (size_t)(colbase + ct * 16 + l15) * CC + t * 32 + lhi * 8);

  float bv0 = 0.f, bv1 = 0.f;
  if (colbase < COUT) {                // U-half columns: fold bias here
    bv0 = bias[colbase + l15];
    bv1 = bias[colbase + 16 + l15];
  }

  short8 aA[4], aB[4];
#pragma unroll
  for (int t = 0; t < 4; ++t)
    aA[t] = *(const short8*)(featbf + (size_t)(row0 + l15) * CC + t * 32 + lhi * 8);

#pragma unroll
  for (int it = 0; it < 4; ++it) {
    short8* cur = (it & 1) ? aB : aA;
    short8* nxt = (it & 1) ? aA : aB;
    if (it < 3) {
      int r = row0 + (it + 1) * 16 + l15;
#pragma unroll
      for (int t = 0; t < 4; ++t)
        nxt[t] = *(const short8*)(featbf + (size_t)r * CC + t * 32 + lhi * 8);
    }
    f32x4 acc0 = {}, acc1 = {};
#pragma unroll
    for (int t = 0; t < 4; ++t) {
      acc0 = __builtin_amdgcn_mfma_f32_16x16x32_bf16(cur[t], wf[t][0], acc0, 0, 0, 0);
      acc1 = __builtin_amdgcn_mfma_f32_16x16x32_bf16(cur[t], wf[t][1], acc1, 0, 0, 0);
    }
    const int orow0 = row0 + it * 16;
#pragma unroll
    for (int i = 0; i < 4; ++i) {
      unsigned short* yr = Y + (size_t)(orow0 + lhi * 4 + i) * 512 + colbase + l15;
      yr[0]  = f2bs(acc0[i] + bv0);
      yr[16] = f2bs(acc1[i] + bv1);
    }
  }
}

// K2: edge phase, TLP-maximized. 8192 blocks x 4 waves; 2 waves per node
// (8 edges each) -> per-wave batch is only 16 loads (32 VGPR) so the compiler
// keeps them all in flight. Halves merged in LDS; stats -> 64-slot partials.
__global__ void __launch_bounds__(256) k2_edge(
    const unsigned short* __restrict__ Y,
    const int* __restrict__ eidx,
    unsigned short* __restrict__ nmaxh, unsigned short* __restrict__ nminh,
    float* __restrict__ gpart)
{
  __shared__ float smx[2][2][256];
  __shared__ float smn[2][2][256];
  __shared__ float ssm[2][2][256];
  __shared__ float sq2[2][2][256];
  const int tid  = threadIdx.x;
  const int wv   = tid >> 6;
  const int lane = tid & 63;
  const int ns   = wv >> 1;                 // node within block (0/1)
  const int hf   = wv & 1;                  // edge half (0/1)
  const int node = blockIdx.x * 2 + ns;
  const int b    = node >> 12;
  const int c0   = lane * 4;
  const unsigned short* Yb = Y + ((size_t)b * NN) * 512;

  const int* ej = eidx + (size_t)node * KK + hf * 8;   // x_j half
  const int* ei = ej + BNK;                            // x_i half
  int4 ej0 = *(const int4*)(ej);
  int4 ej1 = *(const int4*)(ej + 4);
  int4 ei0 = *(const int4*)(ei);
  int4 ei1 = *(const int4*)(ei + 4);
  const int ejr[8] = {ej0.x, ej0.y, ej0.z, ej0.w, ej1.x, ej1.y, ej1.z, ej1.w};
  const int eir[8] = {ei0.x, ei0.y, ei0.z, ei0.w, ei1.x, ei1.y, ei1.z, ei1.w};

  // batch-issue all 16 row loads (independent; fits in ~32 VGPR)
  ushort4 uu[8], vv[8];
#pragma unroll
  for (int e = 0; e < 8; ++e) {
    uu[e] = *(const ushort4*)(Yb + (size_t)eir[e] * 512 + c0);
    vv[e] = *(const ushort4*)(Yb + (size_t)ejr[e] * 512 + 256 + c0);
  }

  float mx[4] = {0.f, 0.f, 0.f, 0.f};
  float mn[4] = {1e30f, 1e30f, 1e30f, 1e30f};
  float sa[4] = {0.f, 0.f, 0.f, 0.f};
  float sb[4] = {0.f, 0.f, 0.f, 0.f};
#pragma unroll
  for (int e = 0; e < 8; ++e) {
    float y0 = fmaxf(bs2f(uu[e].x) + bs2f(vv[e].x), 0.f);
    float y1 = fmaxf(bs2f(uu[e].y) + bs2f(vv[e].y), 0.f);
    float y2 = fmaxf(bs2f(uu[e].z) + bs2f(vv[e].z), 0.f);
    float y3 = fmaxf(bs2f(uu[e].w) + bs2f(vv[e].w), 0.f);
    mx[0] = fmaxf(mx[0], y0); mn[0] = fminf(mn[0], y0); sa[0] += y0; sb[0] += y0 * y0;
    mx[1] = fmaxf(mx[1], y1); mn[1] = fminf(mn[1], y1); sa[1] += y1; sb[1] += y1 * y1;
    mx[2] = fmaxf(mx[2], y2); mn[2] = fminf(mn[2], y2); sa[2] += y2; sb[2] += y2 * y2;
    mx[3] = fmaxf(mx[3], y3); mn[3] = fminf(mn[3], y3); sa[3] += y3; sb[3] += y3 * y3;
  }
#pragma unroll
  for (int m = 0; m < 4; ++m) {
    smx[ns][hf][c0 + m] = mx[m];
    smn[ns][hf][c0 + m] = mn[m];
    ssm[ns][hf][c0 + m] = sa[m];
    sq2[ns][hf][c0 + m] = sb[m];
  }
  __syncthreads();

  // merge: thread tid owns channel c for both nodes
  const int c = tid;
  float bsum = 0.f, bsq = 0.f;
#pragma unroll
  for (int k = 0; k < 2; ++k) {
    float m0 = fmaxf(smx[k][0][c], smx[k][1][c]);
    float n0 = fminf(smn[k][0][c], smn[k][1][c]);
    nmaxh[(size_t)(blockIdx.x * 2 + k) * COUT + c] = f2bs(m0);
    nminh[(size_t)(blockIdx.x * 2 + k) * COUT + c] = f2bs(n0);
    bsum += ssm[k][0][c] + ssm[k][1][c];
    bsq  += sq2[k][0][c] + sq2[k][1][c];
  }
  const int slot = blockIdx.x & 63;
  atomicAdd(&gpart[slot * 256 + c], bsum);
  atomicAdd(&gpart[16384 + slot * 256 + c], bsq);
}

// K3: reduce 64-slot stats partials -> BN affine; monotone max/min select
// (bf16 in) + transposed output.
__global__ void __launch_bounds__(256) k3_out(const unsigned short* __restrict__ nmaxh,
                                              const unsigned short* __restrict__ nminh,
                                              const float* __restrict__ gpart,
                                              const float* __restrict__ gamma,
                                              const float* __restrict__ beta,
                                              float* __restrict__ out) {
  __shared__ float tile[COUT][33];
  int b = blockIdx.x >> 7;
  int n0 = (blockIdx.x & 127) << 5;
  int t = threadIdx.x;
  float s = 0.f, q = 0.f;
#pragma unroll
  for (int u = 0; u < 64; ++u) {
    s += gpart[u * 256 + t];
    q += gpart[16384 + u * 256 + t];
  }
  const float inv = 1.0f / (float)BNK;
  float mean = s * inv;
  float var  = q * inv - mean * mean;
  float sc = gamma[t] * rsqrtf(var + 1e-5f);
  float sh = beta[t] - mean * sc;
  const unsigned short* src = (sc >= 0.f) ? nmaxh : nminh;
#pragma unroll
  for (int rr = 0; rr < 32; ++rr) {
    size_t g = (size_t)(b * NN + n0 + rr) * COUT + t;
    tile[t][rr] = bs2f(src[g]) * sc + sh;
  }
  __syncthreads();
#pragma unroll
  for (int i = 0; i < 32; ++i) {
    int o = i * 8 + (t >> 5);
    int nl = t & 31;
    out[((size_t)(b * COUT + o) * NN) + n0 + nl] = tile[o][nl];
  }
}

extern "C" void kernel_launch(void* const* d_in, const int* in_sizes, int n_in,
                              void* d_out, int out_size, void* d_ws, size_t ws_size,
                              hipStream_t stream) {
  const float* x     = (const float*)d_in[0];
  const float* w     = (const float*)d_in[1];
  const float* bias  = (const float*)d_in[2];
  const float* gamma = (const float*)d_in[3];
  const float* beta  = (const float*)d_in[4];
  const int*   eidx  = (const int*)d_in[5];

  // ws layout (featbf/w12 lifetimes end at k1, overlapped by nmaxh):
  char* ws = (char*)d_ws;
  unsigned short* featbf = (unsigned short*)(ws);              // @0        4,194,304 B (dead after k1)
  unsigned short* w12    = (unsigned short*)(ws + 4194304);    // @4194304    131,072 B (dead after k1)
  unsigned short* nmaxh  = (unsigned short*)(ws);              // @0        8,388,608 B (written in k2)
  unsigned short* Ybuf   = (unsigned short*)(ws + 8388608);    // @8388608 16,777,216 B
  unsigned short* nminh  = (unsigned short*)(ws + 25165824);   // @25165824 8,388,608 B
  float* gpart = (float*)(ws + 33554432);                      //   131,072 B (64-slot sum + sq)
  float* out = (float*)d_out;

  k0_prep<<<256, 256, 0, stream>>>(x, featbf, w, w12, gpart);
  k1_gemm<<<1024, 256, 0, stream>>>(featbf, w12, bias, Ybuf);
  k2_edge<<<8192, 256, 0, stream>>>(Ybuf, eidx, nmaxh, nminh, gpart);
  k3_out<<<512, 256, 0, stream>>>(nmaxh, nminh, gpart, gamma, beta, out);
}